// Round 4
// baseline (382.790 us; speedup 1.0000x reference)
//
#include <hip/hip_runtime.h>
#include <cstdint>
#include <cstddef>

// ---------------------------------------------------------------------------
// out = cos(x @ Wp^T + phi) @ Wc^T
//   x: [32768,1024] fp32, Wp/Wc: [1024,1024] fp32, phi flat [1024] fp32.
// R7: one phase per K-tile. R6 measured 3020 cyc/phase vs 1242 MFMA + 1152
// LDS pipe-time -> ~1600 cyc/phase of barrier+drain overhead at 2 phases per
// tile. Merge kh0+kh1 into a single phase (16 phases/round, 64 MFMA/wave,
// ONE barrier): kh1 ds_reads overlap kh0 MFMAs via compiler-counted lgkmcnt
// (no fence between), staging is a plain 2-deep double buffer issued at
// phase top (issue->vmcnt(0) distance ~2500 cyc >> 900 cyc HBM latency).
// Accumulation order unchanged (bit-identical output).
// ---------------------------------------------------------------------------

typedef __attribute__((ext_vector_type(8))) short short8;
typedef __attribute__((ext_vector_type(4))) float f32x4;

__device__ __forceinline__ unsigned short f2bf(float f) {
  unsigned u = __float_as_uint(f);
  u += 0x7FFFu + ((u >> 16) & 1u);   // RNE
  return (unsigned short)(u >> 16);
}

__device__ __forceinline__ void async_load16(const void* g, const void* l) {
  __builtin_amdgcn_global_load_lds(
      (const __attribute__((address_space(1))) void*)g,
      (__attribute__((address_space(3))) void*)l,
      16, 0, 0);
}

// ------------------- x + Wp + Wc fp32 -> bf16, ONE dispatch -----------------
__global__ __launch_bounds__(256) void cast_all(
    const float* __restrict__ x, const float* __restrict__ Wp,
    const float* __restrict__ Wc, unsigned short* __restrict__ xb,
    unsigned short* __restrict__ wpb, unsigned short* __restrict__ wcb) {
  const long nvec = 35651584 / 8;
  for (long v = (long)blockIdx.x * 256 + threadIdx.x; v < nvec;
       v += (long)gridDim.x * 256) {
    const long i = v * 8;
    const float* s;
    unsigned short* d;
    long j;
    if (i < 33554432)      { s = x;  d = xb;  j = i; }
    else if (i < 34603008) { s = Wp; d = wpb; j = i - 33554432; }
    else                   { s = Wc; d = wcb; j = i - 34603008; }
    const float4 a = *(const float4*)(s + j);
    const float4 b = *(const float4*)(s + j + 4);
    uint4 o;
    o.x = (unsigned)f2bf(a.x) | ((unsigned)f2bf(a.y) << 16);
    o.y = (unsigned)f2bf(a.z) | ((unsigned)f2bf(a.w) << 16);
    o.z = (unsigned)f2bf(b.x) | ((unsigned)f2bf(b.y) << 16);
    o.w = (unsigned)f2bf(b.z) | ((unsigned)f2bf(b.w) << 16);
    *(uint4*)(d + j) = o;
  }
}

constexpr int BM = 256, BN = 256, BK = 64;
constexpr int Kdim = 1024, Ndim = 1024;
constexpr int KT = Kdim / BK;   // 16

// C[m,n] = sum_k A[m,k]*B[n,k]  (B row-major [N,K]).
// EPI==1: store bf16 cos(acc + phi[n]); EPI==0: store fp32 acc.
// 512 threads = 8 waves (2M x 4N); per-wave C tile 128x64.
// LDS: [buf][kh][256 rows][32 kcols] bf16 per matrix (64 KB each).
// T2 swizzle: LDS chunk q of row r holds global 16B-chunk q ^ ((r>>1)&3);
// applied on the GLOBAL source (dest linear, guideline 21), inverted on read.
template <int EPI>
__global__ __launch_bounds__(512, 2) void gemm256(
    const unsigned short* __restrict__ A,   // [M,1024] bf16
    const unsigned short* __restrict__ B,   // [1024,1024] bf16
    const float* __restrict__ phi,
    void* __restrict__ Cout) {
  __shared__ unsigned short As[2][2][256][32];   // 64 KB
  __shared__ unsigned short Bs[2][2][256][32];   // 64 KB

  const int tid    = threadIdx.x;
  const int lane   = tid & 63;
  const int wv     = tid >> 6;        // 0..7
  const int wr     = wv >> 2;         // 0..1  (M wave)
  const int wc     = wv & 3;          // 0..3  (N wave)
  const int lane15 = lane & 15;
  const int quad   = lane >> 4;
  const int swz8   = (quad ^ ((lane15 >> 1) & 3)) * 8;  // ds_read chunk unswizzle

  // Bijective XCD swizzle: 512 wgs = 8 XCDs x 64; 4 n-siblings contiguous so
  // each XCD holds complete A m-panels in its L2.
  const int wg   = ((blockIdx.x & 7) << 6) | (blockIdx.x >> 3);
  const long row0 = (long)(wg >> 2) * BM;
  const int  col0 = (wg & 3) * BN;

  // staging: lane l covers row = wv*32 + l/4 (+16 for 2nd issue), LDS chunk
  // l&3; global source chunk pre-swizzled so LDS dest stays linear.
  const int csrc8 = ((lane & 3) ^ ((lane >> 3) & 3)) * 8;
  const int rA    = wv * 32 + (lane >> 2);

#define SA(KT2, NB, KH)                                                        \
  {                                                                            \
    const unsigned short* g_ =                                                 \
        A + (row0 + rA) * Kdim + (KT2) * BK + (KH) * 32 + csrc8;               \
    async_load16(g_, &As[NB][KH][wv * 32][0]);                                 \
    async_load16(g_ + 16 * Kdim, &As[NB][KH][wv * 32 + 16][0]);                \
  }
#define SB(KT2, NB, KH)                                                        \
  {                                                                            \
    const unsigned short* g_ =                                                 \
        B + (long)(col0 + rA) * Kdim + (KT2) * BK + (KH) * 32 + csrc8;         \
    async_load16(g_, &Bs[NB][KH][wv * 32][0]);                                 \
    async_load16(g_ + 16 * Kdim, &Bs[NB][KH][wv * 32 + 16][0]);                \
  }

  f32x4 acc[8][4];
#pragma unroll
  for (int i = 0; i < 8; ++i)
#pragma unroll
    for (int n = 0; n < 4; ++n) {
      f32x4 z = {0.f, 0.f, 0.f, 0.f};
      acc[i][n] = z;
    }

  // Prologue: stage tile 0 fully into buf 0.
  SA(0, 0, 0); SB(0, 0, 0);
  SA(0, 0, 1); SB(0, 0, 1);
  asm volatile("s_waitcnt vmcnt(0)" ::: "memory");
  __builtin_amdgcn_s_barrier();

#pragma unroll 2
  for (int kt = 0; kt < KT; ++kt) {
    const int cur = kt & 1;
    const int nxt = cur ^ 1;
    short8 af[8], bfr[4];

    // Stage tile kt+1 -> buf nxt (reads of nxt drained at end of phase kt-1).
    // Issued at phase top: ~full phase between issue and the vmcnt(0) below.
    if (kt + 1 < KT) {
      SA(kt + 1, nxt, 0) SB(kt + 1, nxt, 0)
      SA(kt + 1, nxt, 1) SB(kt + 1, nxt, 1)
    }

    // ---- kh0 ----
#pragma unroll
    for (int i = 0; i < 8; ++i)
      af[i] = *(const short8*)(&As[cur][0][wr * 128 + i * 16 + lane15][swz8]);
#pragma unroll
    for (int n = 0; n < 4; ++n)
      bfr[n] = *(const short8*)(&Bs[cur][0][wc * 64 + n * 16 + lane15][swz8]);
    __builtin_amdgcn_s_setprio(1);
#pragma unroll
    for (int i = 0; i < 8; ++i)
#pragma unroll
      for (int n = 0; n < 4; ++n)
        acc[i][n] = __builtin_amdgcn_mfma_f32_16x16x32_bf16(
            af[i], bfr[n], acc[i][n], 0, 0, 0);
    __builtin_amdgcn_s_setprio(0);

    // ---- kh1 (ds_reads overlap kh0 MFMAs; no fence between) ----
#pragma unroll
    for (int i = 0; i < 8; ++i)
      af[i] = *(const short8*)(&As[cur][1][wr * 128 + i * 16 + lane15][swz8]);
#pragma unroll
    for (int n = 0; n < 4; ++n)
      bfr[n] = *(const short8*)(&Bs[cur][1][wc * 64 + n * 16 + lane15][swz8]);
    __builtin_amdgcn_s_setprio(1);
#pragma unroll
    for (int i = 0; i < 8; ++i)
#pragma unroll
      for (int n = 0; n < 4; ++n)
        acc[i][n] = __builtin_amdgcn_mfma_f32_16x16x32_bf16(
            af[i], bfr[n], acc[i][n], 0, 0, 0);
    __builtin_amdgcn_s_setprio(0);

    // Phase end: lgkm drain (WAR: next phase stages into [cur]) + vmcnt(0)
    // (tile kt+1 resident) behind ONE barrier.
    asm volatile("s_waitcnt vmcnt(0) lgkmcnt(0)" ::: "memory");
    __builtin_amdgcn_sched_barrier(0);
    __builtin_amdgcn_s_barrier();
  }
#undef SA
#undef SB

  // C/D layout (m89-verified): col = lane&15, row = quad*4 + reg.
  if (EPI == 1) {
    unsigned short* Q = (unsigned short*)Cout;
    float ph[4];
#pragma unroll
    for (int n = 0; n < 4; ++n)
      ph[n] = phi[col0 + wc * 64 + n * 16 + lane15];
#pragma unroll
    for (int mi = 0; mi < 8; ++mi) {
      const long rbase = row0 + wr * 128 + mi * 16 + quad * 4;
#pragma unroll
      for (int n = 0; n < 4; ++n) {
        const int c = col0 + wc * 64 + n * 16 + lane15;
#pragma unroll
        for (int r = 0; r < 4; ++r) {
          float v = __cosf(acc[mi][n][r] + ph[n]);
          Q[(rbase + r) * Ndim + c] = f2bf(v);
        }
      }
    }
  } else {
    float* C = (float*)Cout;
#pragma unroll
    for (int mi = 0; mi < 8; ++mi) {
      const long rbase = row0 + wr * 128 + mi * 16 + quad * 4;
#pragma unroll
      for (int n = 0; n < 4; ++n) {
        const int c = col0 + wc * 64 + n * 16 + lane15;
#pragma unroll
        for (int r = 0; r < 4; ++r)
          C[(rbase + r) * Ndim + c] = acc[mi][n][r];
      }
    }
  }
}

// ------------------------------- launch -------------------------------------
extern "C" void kernel_launch(void* const* d_in, const int* in_sizes, int n_in,
                              void* d_out, int out_size, void* d_ws, size_t ws_size,
                              hipStream_t stream) {
  const float* x   = (const float*)d_in[0];
  const float* Wp  = (const float*)d_in[1];
  const float* Wc  = (const float*)d_in[2];
  const float* phi = (const float*)d_in[3];
  float* out = (float*)d_out;

  // ws: Abf @0 (64 MB), Qbf @64 MB (64 MB), Wpbf @128 MB (2 MB), Wcbf (2 MB)
  char* ws = (char*)d_ws;
  unsigned short* Abf  = (unsigned short*)(ws);
  unsigned short* Qbf  = (unsigned short*)(ws + (size_t)67108864);
  unsigned short* Wpbf = (unsigned short*)(ws + (size_t)134217728);
  unsigned short* Wcbf = (unsigned short*)(ws + (size_t)136314880);

  cast_all<<<4096, 256, 0, stream>>>(x, Wp, Wc, Abf, Wpbf, Wcbf);
  gemm256<1><<<512, 512, 0, stream>>>(Abf, Wpbf, phi, (void*)Qbf);
  gemm256<0><<<512, 512, 0, stream>>>(Qbf, Wcbf, nullptr, (void*)out);

  (void)in_sizes; (void)n_in; (void)out_size; (void)ws_size;
}